// Round 5
// baseline (689.678 us; speedup 1.0000x reference)
//
#include <hip/hip_runtime.h>

#define N_NODES 50000
#define N_EDGES 800000
#define NUM_GRAPHS 16
#define NUM_CLASSES 247
#define SCAN_BLOCKS ((N_NODES + 255) / 256)  // 196
#define CSR_CAP (N_EDGES + 7 * N_NODES)      // degrees padded to multiples of 8
#define PREP_BLOCKS 512                      // 2 blocks/CU guaranteed resident

typedef __attribute__((ext_vector_type(8))) short bf16x8;
typedef __attribute__((ext_vector_type(4))) float f32x4;

static inline int nblk(long n) { return (int)((n + 255) / 256); }

__device__ __forceinline__ float bfl(unsigned short u) {
    return __uint_as_float((unsigned)u << 16);
}
__device__ __forceinline__ unsigned short bf16_rne(float f) {
    unsigned u = __float_as_uint(f);
    u += 0x7FFF + ((u >> 16) & 1);
    return (unsigned short)(u >> 16);
}

// ---- unsigned e4m4 (bias 7) quantization for post-ReLU activations --------
// Stored values carry a x64 scale shift (folded into producer epilogue);
// Wt2/Wt3 are pre-divided by 64 so the GEMM result is true-scale.
__device__ __forceinline__ unsigned q8(float v) {
    if (v < 0.015625f) return 0u;
    unsigned u = __float_as_uint(v) - (120u << 23);
    u += 0x3FFFF + ((u >> 19) & 1);
    unsigned q = u >> 19;
    return q > 255u ? 255u : q;
}
__device__ __forceinline__ float dq8(unsigned x) {
    float f = __uint_as_float((x + 1920u) << 19);
    return x ? f : 0.0f;
}

// ---- device-scope grid barrier (all PREP_BLOCKS co-resident by bounds) -----
__device__ __forceinline__ void gridbar(int* bar, int id, int nb) {
    __threadfence();   // release: each thread's writes visible device-wide
    __syncthreads();
    if (threadIdx.x == 0) {
        if (atomicAdd(&bar[2 * id], 1) == nb - 1) {
            atomicExch(&bar[2 * id + 1], 1);
        } else {
            while (atomicAdd(&bar[2 * id + 1], 0) == 0)
                __builtin_amdgcn_s_sleep(16);
        }
    }
    __syncthreads();
    __threadfence();   // acquire: invalidate stale cached lines
}

// ---- ONE persistent kernel: zeroing + degree hist + scan + CSR fill + L1 ---
// Replaces 4 memsets + k_deg + k_scan1 + k_scan3 + k_fill + k_layer1
// (9 dispatch boundaries reclaimed). Stage bodies are verbatim copies of the
// verified standalone kernels; only the iteration wrappers changed.
__global__ __launch_bounds__(256, 2) void k_prep(
        const int* __restrict__ col, const int* __restrict__ row,
        const int* __restrict__ batch, const float* __restrict__ x,
        const float* __restrict__ W1, const float* __restrict__ b1,
        const float* __restrict__ W2, const float* __restrict__ W3,
        int* __restrict__ degc, int* __restrict__ pos,
        int* __restrict__ rowptr, int* __restrict__ bsum,
        int* __restrict__ base, float* __restrict__ dinv,
        float* __restrict__ xs, unsigned short* __restrict__ Wt2,
        unsigned short* __restrict__ Wt3, int* __restrict__ csr,
        float* __restrict__ psum, unsigned char* __restrict__ X,
        unsigned char* __restrict__ Y, int* __restrict__ bar) {
    __shared__ int s_buf[256];
    __shared__ int s_hist[NUM_GRAPHS];
    __shared__ int s_red[256];
    const int nb = gridDim.x;
    const int nthr = nb * 256;
    const int tid = blockIdx.x * 256 + threadIdx.x;
    float* pcnt = psum + NUM_GRAPHS * 256;

    // ---- stage A: zero degc, psum+pcnt, X/Y sentinel rows ----
    for (int i = tid; i < 8 * N_NODES; i += nthr) degc[i] = 0;
    for (int i = tid; i < NUM_GRAPHS * 256 + NUM_GRAPHS; i += nthr) psum[i] = 0.0f;
    if (tid < 64) X[(size_t)N_NODES * 64 + tid] = 0;
    if (tid < 128) Y[(size_t)N_NODES * 128 + tid] = 0;
    gridbar(bar, 0, nb);

    // ---- stage B: degree histogram into 8 XCD-local copies ----
    for (int e = tid; e < N_EDGES; e += nthr) {
        int c8 = (e >> 8) & 7;
        pos[e] = atomicAdd(&degc[c8 * N_NODES + col[e]], 1);
    }
    gridbar(bar, 1, nb);

    // ---- stage C1: per-chunk exclusive scan of padded degree + batch hist --
    if (blockIdx.x < SCAN_BLOCKS) {
        int t = threadIdx.x;
        if (t < NUM_GRAPHS) s_hist[t] = 0;
        __syncthreads();
        int i = blockIdx.x * 256 + t;
        int v = 0;
        if (i < N_NODES) {
            int tot = 0;
#pragma unroll
            for (int c = 0; c < 8; ++c) tot += degc[c * N_NODES + i];
            v = (tot + 7) & ~7;  // padded degree
            atomicAdd(&s_hist[batch[i]], 1);
        }
        s_buf[t] = v;
        __syncthreads();
#pragma unroll
        for (int off = 1; off < 256; off <<= 1) {
            int tmp = (t >= off) ? s_buf[t - off] : 0;
            __syncthreads();
            if (t >= off) s_buf[t] += tmp;
            __syncthreads();
        }
        if (i < N_NODES) rowptr[i] = s_buf[t] - v;  // exclusive within chunk
        if (t == 255) bsum[blockIdx.x] = s_buf[255];
        if (t < NUM_GRAPHS && s_hist[t] > 0) atomicAdd(&pcnt[t], (float)s_hist[t]);
    }
    gridbar(bar, 2, nb);

    // ---- stage C2: chunk offsets + per-copy bases + dinv + xs + Wt casts ---
    if (blockIdx.x < SCAN_BLOCKS) {
        int t = threadIdx.x;
        int b = blockIdx.x;
        s_red[t] = (t < b) ? bsum[t] : 0;  // b <= 195 < 256
        __syncthreads();
#pragma unroll
        for (int off = 128; off > 0; off >>= 1) {
            if (t < off) s_red[t] += s_red[t + off];
            __syncthreads();
        }
        int boff = s_red[0];
        int i = b * 256 + t;
        if (i < N_NODES) {
            int rp = rowptr[i] + boff;
            rowptr[i] = rp;
            int run = rp, tot = 0;
#pragma unroll
            for (int c = 0; c < 8; ++c) {
                int d = degc[c * N_NODES + i];
                base[c * N_NODES + i] = run;
                run += d;
                tot += d;
            }
            int pdeg = (tot + 7) & ~7;
            for (int j = rp + tot; j < rp + pdeg; ++j) csr[j] = N_NODES;
            if (i == N_NODES - 1) rowptr[N_NODES] = rp + pdeg;
            float dv = rsqrtf((float)tot + 1.0f);  // +1 = self loop
            dinv[i] = dv;
            xs[i * 3 + 0] = dv * x[i * 3 + 0];
            xs[i * 3 + 1] = dv * x[i * 3 + 1];
            xs[i * 3 + 2] = dv * x[i * 3 + 2];
        }
        if (i == 0) {
            xs[3 * N_NODES + 0] = 0.0f;
            xs[3 * N_NODES + 1] = 0.0f;
            xs[3 * N_NODES + 2] = 0.0f;
        }
        // folded weight cast+transpose (with /64 e4m4 scale compensation)
        if (i < 64 * 128) {                       // Wt2: [f=128][k=64]
            int f = i / 64, k = i % 64;
            Wt2[i] = bf16_rne(W2[k * 128 + f] * 0.015625f);
        } else if (i < 64 * 128 + 128 * 256) {    // Wt3: [f=256][k=128]
            int j = i - 64 * 128;
            int f = j / 128, k = j % 128;
            Wt3[j] = bf16_rne(W3[k * 256 + f] * 0.015625f);
        }
    }
    gridbar(bar, 3, nb);

    // ---- stage D: CSR fill (no atomic; slot = base[copy][dst] + rank) ------
    for (int e = tid; e < N_EDGES; e += nthr) {
        int c8 = (e >> 8) & 7;
        csr[base[c8 * N_NODES + col[e]] + pos[e]] = row[e];
    }
    gridbar(bar, 4, nb);

    // ---- stage E: fused layer 1 (verbatim k_layer1 body, node-per-thread) --
    {
        int v = tid;
        if (v < N_NODES) {
            float a0 = xs[v * 3 + 0];
            float a1 = xs[v * 3 + 1];
            float a2 = xs[v * 3 + 2];
            int j = rowptr[v];
            int j1 = rowptr[v + 1];
            for (; j + 4 <= j1; j += 4) {
                int r0 = csr[j + 0], r1 = csr[j + 1];
                int r2 = csr[j + 2], r3 = csr[j + 3];
                float x00 = xs[r0 * 3 + 0], x01 = xs[r0 * 3 + 1], x02 = xs[r0 * 3 + 2];
                float x10 = xs[r1 * 3 + 0], x11 = xs[r1 * 3 + 1], x12 = xs[r1 * 3 + 2];
                float x20 = xs[r2 * 3 + 0], x21 = xs[r2 * 3 + 1], x22 = xs[r2 * 3 + 2];
                float x30 = xs[r3 * 3 + 0], x31 = xs[r3 * 3 + 1], x32 = xs[r3 * 3 + 2];
                a0 += x00; a1 += x01; a2 += x02;
                a0 += x10; a1 += x11; a2 += x12;
                a0 += x20; a1 += x21; a2 += x22;
                a0 += x30; a1 += x31; a2 += x32;
            }
            for (; j < j1; ++j) {  // dead with padded degrees
                int r = csr[j];
                a0 += xs[r * 3 + 0];
                a1 += xs[r * 3 + 1];
                a2 += xs[r * 3 + 2];
            }
            float dv = dinv[v];
            float p0 = dv * a0, p1 = dv * a1, p2 = dv * a2;
            float dv64 = dv * 64.0f;  // pre-scale for next prop + e4m4 shift
            unsigned char* ov = X + (long)v * 64;
#pragma unroll
            for (int f = 0; f < 64; f += 4) {
                unsigned pk = 0;
#pragma unroll
                for (int t = 0; t < 4; ++t) {
                    float s = fmaf(p0, W1[f + t],
                              fmaf(p1, W1[64 + f + t],
                              fmaf(p2, W1[128 + f + t], b1[f + t])));
                    s = fmaxf(s, 0.0f) * dv64;
                    pk |= q8(s) << (8 * t);
                }
                *(unsigned*)(ov + f) = pk;
            }
        }
    }
}

// ---- FUSED prop + MFMA GEMM per 16-row m-tile (BYTE-IDENTICAL to R4) -------
template <int K, int F, bool PRESCALE, bool POOL>
__global__ __launch_bounds__(256) void k_fused(
        const unsigned char* __restrict__ h, const float* __restrict__ dinv,
        const int* __restrict__ rowptr, const int* __restrict__ csr_src,
        const unsigned short* __restrict__ Wt, const float* __restrict__ b,
        unsigned char* __restrict__ out, const int* __restrict__ batch,
        float* __restrict__ psum, int N) {
    constexpr int NF = F / 16;    // f-tiles: 8 (F=128) / 16 (F=256)
    constexpr int FPW = NF / 4;   // f-tiles per wave: 2 / 4
    constexpr int KB = K / 32;    // k-blocks: 2 / 4
    constexpr int KL = K / 64;    // features (bytes) per lane in prop: 1 / 2
    constexpr int PADK = K + 8;
    __shared__ unsigned short plds[16][PADK];
    int wave = threadIdx.x >> 6;
    int lane = threadIdx.x & 63;
    int m0 = blockIdx.x * 16;

    // ---- phase 1: propagation into LDS, rows processed in pairs ----
    for (int pr = 0; pr < 2; ++pr) {
        int va = m0 + wave * 4 + pr * 2;
        int vb = va + 1;
        float acca[KL], accb[KL];
        const unsigned char* hva = h + (long)va * K + lane * KL;
        const unsigned char* hvb = h + (long)vb * K + lane * KL;
        if (KL == 2) {
            unsigned ua = *(const unsigned short*)hva;
            unsigned ub = *(const unsigned short*)hvb;
            acca[0] = dq8(ua & 0xff);
            acca[1] = dq8(ua >> 8);
            accb[0] = dq8(ub & 0xff);
            accb[1] = dq8(ub >> 8);
        } else {
            acca[0] = dq8(hva[0]);
            accb[0] = dq8(hvb[0]);
        }
        int ja  = __builtin_amdgcn_readfirstlane(rowptr[va]);
        int j1a = __builtin_amdgcn_readfirstlane(rowptr[va + 1]);
        int jb  = j1a;
        int j1b = __builtin_amdgcn_readfirstlane(rowptr[vb + 1]);
        while (ja + 8 <= j1a && jb + 8 <= j1b) {
            int ra[8], rb[8];
#pragma unroll
            for (int u = 0; u < 8; ++u) ra[u] = csr_src[ja + u];
#pragma unroll
            for (int u = 0; u < 8; ++u) rb[u] = csr_src[jb + u];
            if (KL == 2) {
                unsigned ta[8], tb[8];
#pragma unroll
                for (int u = 0; u < 8; ++u)
                    ta[u] = *(const unsigned short*)(h + (long)ra[u] * K + lane * 2);
#pragma unroll
                for (int u = 0; u < 8; ++u)
                    tb[u] = *(const unsigned short*)(h + (long)rb[u] * K + lane * 2);
#pragma unroll
                for (int u = 0; u < 8; ++u) {
                    acca[0] += dq8(ta[u] & 0xff);
                    acca[1] += dq8(ta[u] >> 8);
                }
#pragma unroll
                for (int u = 0; u < 8; ++u) {
                    accb[0] += dq8(tb[u] & 0xff);
                    accb[1] += dq8(tb[u] >> 8);
                }
            } else {
                unsigned char ta[8], tb[8];
#pragma unroll
                for (int u = 0; u < 8; ++u) ta[u] = h[(long)ra[u] * K + lane];
#pragma unroll
                for (int u = 0; u < 8; ++u) tb[u] = h[(long)rb[u] * K + lane];
#pragma unroll
                for (int u = 0; u < 8; ++u) acca[0] += dq8(ta[u]);
#pragma unroll
                for (int u = 0; u < 8; ++u) accb[0] += dq8(tb[u]);
            }
            ja += 8;
            jb += 8;
        }
        for (; ja + 8 <= j1a; ja += 8) {
            int r[8];
#pragma unroll
            for (int u = 0; u < 8; ++u) r[u] = csr_src[ja + u];
            if (KL == 2) {
                unsigned tv[8];
#pragma unroll
                for (int u = 0; u < 8; ++u)
                    tv[u] = *(const unsigned short*)(h + (long)r[u] * K + lane * 2);
#pragma unroll
                for (int u = 0; u < 8; ++u) {
                    acca[0] += dq8(tv[u] & 0xff);
                    acca[1] += dq8(tv[u] >> 8);
                }
            } else {
                unsigned char tv[8];
#pragma unroll
                for (int u = 0; u < 8; ++u) tv[u] = h[(long)r[u] * K + lane];
#pragma unroll
                for (int u = 0; u < 8; ++u) acca[0] += dq8(tv[u]);
            }
        }
        for (; ja < j1a; ++ja) {  // dead with padded degrees
            int r = csr_src[ja];
            if (KL == 2) {
                unsigned u = *(const unsigned short*)(h + (long)r * K + lane * 2);
                acca[0] += dq8(u & 0xff);
                acca[1] += dq8(u >> 8);
            } else {
                acca[0] += dq8(h[(long)r * K + lane]);
            }
        }
        for (; jb + 8 <= j1b; jb += 8) {
            int r[8];
#pragma unroll
            for (int u = 0; u < 8; ++u) r[u] = csr_src[jb + u];
            if (KL == 2) {
                unsigned tv[8];
#pragma unroll
                for (int u = 0; u < 8; ++u)
                    tv[u] = *(const unsigned short*)(h + (long)r[u] * K + lane * 2);
#pragma unroll
                for (int u = 0; u < 8; ++u) {
                    accb[0] += dq8(tv[u] & 0xff);
                    accb[1] += dq8(tv[u] >> 8);
                }
            } else {
                unsigned char tv[8];
#pragma unroll
                for (int u = 0; u < 8; ++u) tv[u] = h[(long)r[u] * K + lane];
#pragma unroll
                for (int u = 0; u < 8; ++u) accb[0] += dq8(tv[u]);
            }
        }
        for (; jb < j1b; ++jb) {  // dead with padded degrees
            int r = csr_src[jb];
            if (KL == 2) {
                unsigned u = *(const unsigned short*)(h + (long)r * K + lane * 2);
                accb[0] += dq8(u & 0xff);
                accb[1] += dq8(u >> 8);
            } else {
                accb[0] += dq8(h[(long)r * K + lane]);
            }
        }
        float da = dinv[va];
        float db = dinv[vb];
        int rla = wave * 4 + pr * 2;
        if (KL == 2) {
            unsigned pa = (unsigned)bf16_rne(da * acca[0]) | ((unsigned)bf16_rne(da * acca[1]) << 16);
            unsigned pb = (unsigned)bf16_rne(db * accb[0]) | ((unsigned)bf16_rne(db * accb[1]) << 16);
            *(unsigned*)&plds[rla][lane * 2] = pa;
            *(unsigned*)&plds[rla + 1][lane * 2] = pb;
        } else {
            plds[rla][lane] = bf16_rne(da * acca[0]);
            plds[rla + 1][lane] = bf16_rne(db * accb[0]);
        }
    }
    __syncthreads();

    // ---- phase 2: MFMA (layout verified R9/R11) ----
    int quad = lane >> 4;
    int l16 = lane & 15;
    bf16x8 afr[KB];
#pragma unroll
    for (int kb = 0; kb < KB; ++kb)
        afr[kb] = *(const bf16x8*)(const void*)&plds[l16][kb * 32 + quad * 8];
#pragma unroll
    for (int fi = 0; fi < FPW; ++fi) {
        int f0 = (wave * FPW + fi) * 16;
        const unsigned short* wrow = Wt + (long)(f0 + l16) * K + quad * 8;
        f32x4 acc4 = {0.f, 0.f, 0.f, 0.f};
#pragma unroll
        for (int kb = 0; kb < KB; ++kb) {
            bf16x8 bb = *(const bf16x8*)(const void*)(wrow + kb * 32);
            acc4 = __builtin_amdgcn_mfma_f32_16x16x32_bf16(afr[kb], bb, acc4, 0, 0, 0);
        }
        float bias = b[f0 + l16];
        if (POOL) {
            int g0 = batch[m0];
            int g15 = batch[m0 + 15];
            if (g0 == g15) {  // uniform block (all but ~15 of 3125)
                float s = fmaxf(acc4[0] + bias, 0.0f);
                s += fmaxf(acc4[1] + bias, 0.0f);
                s += fmaxf(acc4[2] + bias, 0.0f);
                s += fmaxf(acc4[3] + bias, 0.0f);
                s += __shfl_xor(s, 16);
                s += __shfl_xor(s, 32);
                if (quad == 0) atomicAdd(&psum[g0 * 256 + f0 + l16], s);
            } else {  // graph boundary inside block: per-element atomics
#pragma unroll
                for (int r = 0; r < 4; ++r) {
                    int m = m0 + quad * 4 + r;
                    float val = fmaxf(acc4[r] + bias, 0.0f);
                    atomicAdd(&psum[batch[m] * 256 + f0 + l16], val);
                }
            }
        } else {
#pragma unroll
            for (int r = 0; r < 4; ++r) {
                int m = m0 + quad * 4 + r;
                float val = fmaxf(acc4[r] + bias, 0.0f);
                if (PRESCALE) val *= dinv[m] * 64.0f;  // prop pre-scale + e4m4 shift
                out[(long)m * F + f0 + l16] = (unsigned char)q8(val);
            }
        }
    }
}

// ---- final FC --------------------------------------------------------------
__global__ void k_fc(const float* __restrict__ psum, const float* __restrict__ pcnt,
                     const float* __restrict__ Wfc, const float* __restrict__ bfc,
                     float* __restrict__ out) {
    int tid = blockIdx.x * blockDim.x + threadIdx.x;
    if (tid >= NUM_GRAPHS * NUM_CLASSES) return;
    int g = tid / NUM_CLASSES;
    int c = tid % NUM_CLASSES;
    float s = 0.0f;
#pragma unroll 8
    for (int k = 0; k < 256; ++k) s = fmaf(psum[g * 256 + k], Wfc[k * NUM_CLASSES + c], s);
    float cnt = pcnt[g];
    cnt = cnt > 1.0f ? cnt : 1.0f;
    out[tid] = s / cnt + bfc[c];
}

extern "C" void kernel_launch(void* const* d_in, const int* in_sizes, int n_in,
                              void* d_out, int out_size, void* d_ws, size_t ws_size,
                              hipStream_t stream) {
    const float* x     = (const float*)d_in[0];
    const int*   ei    = (const int*)d_in[1];
    const int*   batch = (const int*)d_in[2];
    const float* W1    = (const float*)d_in[3];
    const float* b1    = (const float*)d_in[4];
    const float* W2    = (const float*)d_in[5];
    const float* b2    = (const float*)d_in[6];
    const float* W3    = (const float*)d_in[7];
    const float* b3    = (const float*)d_in[8];
    const float* Wfc   = (const float*)d_in[9];
    const float* bfc   = (const float*)d_in[10];
    float* out = (float*)d_out;

    const int* row = ei;            // src
    const int* col = ei + N_EDGES;  // dst

    // workspace layout, 16B-aligned; sentinel row at index N_NODES.
    float*  xs   = (float*)d_ws;                         // (N+1)*3 f32 (padded to 150004)
    float*  dinv = xs + 150004;                          // N
    float*  psum = dinv + N_NODES;                       // 16*256
    float*  pcnt = psum + NUM_GRAPHS * 256;              // 16
    unsigned char* X = (unsigned char*)(pcnt + NUM_GRAPHS);      // (N+1)*64 B
    unsigned char* Y = X + (size_t)(N_NODES + 1) * 64;           // (N+1)*128 B
    unsigned short* Wt2 = (unsigned short*)(Y + (size_t)(N_NODES + 1) * 128);  // 128*64
    unsigned short* Wt3 = Wt2 + 128 * 64;                        // 256*128
    int* degc   = (int*)(Wt3 + 256 * 128);               // 8*N (XCD-local copies)
    int* base   = degc + 8 * N_NODES;                    // 8*N (per-copy slot bases)
    int* rowptr = base + 8 * N_NODES;                    // N+1
    int* csrsrc = rowptr + N_NODES + 1;                  // CSR_CAP (padded)
    int* pos    = csrsrc + CSR_CAP;                      // E
    int* bsum   = pos + N_EDGES;                         // SCAN_BLOCKS
    int* bar    = bsum + SCAN_BLOCKS;                    // 16 (grid barrier state)

    // only the tiny barrier state needs a host-side reset
    hipMemsetAsync(bar, 0, 16 * sizeof(int), stream);

    // ---- fused preprocessing: zero + deg + scan + fill + layer1 ------------
    k_prep<<<PREP_BLOCKS, 256, 0, stream>>>(
        col, row, batch, x, W1, b1, W2, W3,
        degc, pos, rowptr, bsum, base, dinv, xs, Wt2, Wt3,
        csrsrc, psum, X, Y, bar);

    int mtiles = N_NODES / 16;  // 3125, exact

    // ---- layer 2 fused: Y = q8(64*d*relu((A~-apply X) W2 + b2)) ------------
    k_fused<64, 128, true, false><<<mtiles, 256, 0, stream>>>(
        X, dinv, rowptr, csrsrc, Wt2, b2, Y, batch, psum, N_NODES);

    // ---- layer 3 fused + POOL: psum += relu((A~-apply Y) W3 + b3) ----------
    k_fused<128, 256, false, true><<<mtiles, 256, 0, stream>>>(
        Y, dinv, rowptr, csrsrc, Wt3, b3, (unsigned char*)nullptr, batch, psum, N_NODES);

    // ---- FC ----
    k_fc<<<nblk(NUM_GRAPHS * NUM_CLASSES), 256, 0, stream>>>(psum, pcnt, Wfc, bfc, out);
}

// Round 6
// 238.106 us; speedup vs baseline: 2.8965x; 2.8965x over previous
//
#include <hip/hip_runtime.h>

#define N_NODES 50000
#define N_EDGES 800000
#define NUM_GRAPHS 16
#define NUM_CLASSES 247
#define SCAN_BLOCKS ((N_NODES + 255) / 256)  // 196
#define CSR_CAP (N_EDGES + 7 * N_NODES)      // degrees padded to multiples of 8

typedef __attribute__((ext_vector_type(8))) short bf16x8;
typedef __attribute__((ext_vector_type(4))) float f32x4;
typedef __attribute__((ext_vector_type(2))) float f32x2;

#if __has_builtin(__builtin_amdgcn_cvt_pk_f32_fp8) && __has_builtin(__builtin_amdgcn_cvt_pk_fp8_f32)
#define HW_FP8 1
#else
#define HW_FP8 0
#endif

static inline int nblk(long n) { return (int)((n + 255) / 256); }

__device__ __forceinline__ float bfl(unsigned short u) {
    return __uint_as_float((unsigned)u << 16);
}
__device__ __forceinline__ unsigned short bf16_rne(float f) {
    unsigned u = __float_as_uint(f);
    u += 0x7FFF + ((u >> 16) & 1);
    return (unsigned short)(u >> 16);
}

// ---- 8-bit activation codec -------------------------------------------------
// Preferred: HW fp8 e4m3 (v_cvt_pk_*): 1 VALU op per 2 features, RNE, HW
// denormals. Fallback: R4's software unsigned-e4m4. Either way values carry a
// x64 scale shift (encoded in producers); Wt2/Wt3 are pre-divided by 64.
__device__ __forceinline__ unsigned q8(float v) {  // sw e4m4 (fallback)
    if (v < 0.015625f) return 0u;
    unsigned u = __float_as_uint(v) - (120u << 23);
    u += 0x3FFFF + ((u >> 19) & 1);
    unsigned q = u >> 19;
    return q > 255u ? 255u : q;
}
__device__ __forceinline__ float dq8(unsigned x) {  // sw e4m4 (fallback)
    float f = __uint_as_float((x + 1920u) << 19);
    return x ? f : 0.0f;
}

__device__ __forceinline__ void dq2(unsigned v, float& lo, float& hi) {
#if HW_FP8
    f32x2 t = __builtin_amdgcn_cvt_pk_f32_fp8((int)v, false);
    lo = t[0];
    hi = t[1];
#else
    lo = dq8(v & 0xff);
    hi = dq8(v >> 8);
#endif
}
__device__ __forceinline__ float dq1(unsigned v) {
#if HW_FP8
    f32x2 t = __builtin_amdgcn_cvt_pk_f32_fp8((int)(v & 0xff), false);
    return t[0];
#else
    return dq8(v & 0xff);
#endif
}
__device__ __forceinline__ unsigned enc1(float v) {
#if HW_FP8
    return (unsigned)__builtin_amdgcn_cvt_pk_fp8_f32(v, 0.0f, 0, false) & 0xffu;
#else
    return q8(v);
#endif
}
__device__ __forceinline__ unsigned enc4(float a, float b, float c, float d) {
#if HW_FP8
    int r = __builtin_amdgcn_cvt_pk_fp8_f32(a, b, 0, false);
    r = __builtin_amdgcn_cvt_pk_fp8_f32(c, d, r, true);
    return (unsigned)r;
#else
    return q8(a) | (q8(b) << 8) | (q8(c) << 16) | (q8(d) << 24);
#endif
}

// ---- degree histogram into 8 XCD-local copies; returns rank within copy ----
// Block 0 additionally zeroes psum/pcnt + X/Y sentinel rows (stream-ordered
// before all their consumers) — replaces 3 hipMemsetAsync dispatches.
__global__ void k_deg(const int* __restrict__ col, int* __restrict__ degc,
                      int* __restrict__ pos, float* __restrict__ psum,
                      unsigned char* __restrict__ X, unsigned char* __restrict__ Y,
                      int E) {
    if (blockIdx.x == 0) {
        for (int i = threadIdx.x; i < NUM_GRAPHS * 256 + NUM_GRAPHS; i += 256)
            psum[i] = 0.0f;
        if (threadIdx.x < 64) X[(size_t)N_NODES * 64 + threadIdx.x] = 0;
        if (threadIdx.x < 128) Y[(size_t)N_NODES * 128 + threadIdx.x] = 0;
    }
    int e = blockIdx.x * blockDim.x + threadIdx.x;
    if (e >= E) return;
    int c8 = (e >> 8) & 7;
    pos[e] = atomicAdd(&degc[c8 * N_NODES + col[e]], 1);
}

// ---- scan phase 1: per-block exclusive scan of PADDED degree + batch hist --
__global__ __launch_bounds__(256) void k_scan1(const int* __restrict__ degc,
                                               int* __restrict__ rowptr,
                                               int* __restrict__ bsum,
                                               const int* __restrict__ batch,
                                               float* __restrict__ pcnt, int N) {
    __shared__ int buf[256];
    __shared__ int hist[NUM_GRAPHS];
    int t = threadIdx.x;
    if (t < NUM_GRAPHS) hist[t] = 0;
    __syncthreads();  // hist must be zeroed before any wave's atomicAdd
    int i = blockIdx.x * 256 + t;
    int v = 0;
    if (i < N) {
        int tot = 0;
#pragma unroll
        for (int c = 0; c < 8; ++c) tot += degc[c * N_NODES + i];
        v = (tot + 7) & ~7;  // padded degree
        atomicAdd(&hist[batch[i]], 1);
    }
    buf[t] = v;
    __syncthreads();
#pragma unroll
    for (int off = 1; off < 256; off <<= 1) {
        int tmp = (t >= off) ? buf[t - off] : 0;
        __syncthreads();
        if (t >= off) buf[t] += tmp;
        __syncthreads();
    }
    if (i < N) rowptr[i] = buf[t] - v;  // exclusive within block
    if (t == 255) bsum[blockIdx.x] = buf[255];
    if (t < NUM_GRAPHS && hist[t] > 0) atomicAdd(&pcnt[t], (float)hist[t]);
}

// ---- scan phase 2 (folded): block-offset + per-copy bases + dinv + xs + Wt
//      + sentinel-fill of the pad slots + rowptr[N] --------------------------
// Wt2/Wt3 are cast to bf16 with a /64 scale (exact: exponent shift only) to
// compensate the x64 scale shift in the 8-bit activations.
__global__ __launch_bounds__(256) void k_scan3(int* __restrict__ rowptr,
                                               const int* __restrict__ bsum,
                                               const int* __restrict__ degc,
                                               int* __restrict__ base,
                                               float* __restrict__ dinv,
                                               const float* __restrict__ x,
                                               float* __restrict__ xs,
                                               int* __restrict__ csr,
                                               const float* __restrict__ W2,
                                               const float* __restrict__ W3,
                                               unsigned short* __restrict__ Wt2,
                                               unsigned short* __restrict__ Wt3,
                                               int N) {
    __shared__ int red[256];
    int t = threadIdx.x;
    int b = blockIdx.x;
    red[t] = (t < b) ? bsum[t] : 0;  // b <= 195 < 256
    __syncthreads();
#pragma unroll
    for (int off = 128; off > 0; off >>= 1) {
        if (t < off) red[t] += red[t + off];
        __syncthreads();
    }
    int boff = red[0];
    int i = b * 256 + t;
    if (i < N) {
        int rp = rowptr[i] + boff;
        rowptr[i] = rp;
        int run = rp, tot = 0;
#pragma unroll
        for (int c = 0; c < 8; ++c) {
            int d = degc[c * N_NODES + i];
            base[c * N_NODES + i] = run;
            run += d;
            tot += d;
        }
        int pdeg = (tot + 7) & ~7;
        // sentinel-fill pad slots -> point at the all-zero row N_NODES
        for (int j = rp + tot; j < rp + pdeg; ++j) csr[j] = N_NODES;
        if (i == N - 1) rowptr[N] = rp + pdeg;  // padded total
        float dv = rsqrtf((float)tot + 1.0f);   // +1 = self loop
        dinv[i] = dv;
        xs[i * 3 + 0] = dv * x[i * 3 + 0];
        xs[i * 3 + 1] = dv * x[i * 3 + 1];
        xs[i * 3 + 2] = dv * x[i * 3 + 2];
    }
    if (i == 0) {  // zero sentinel row of xs
        xs[3 * N_NODES + 0] = 0.0f;
        xs[3 * N_NODES + 1] = 0.0f;
        xs[3 * N_NODES + 2] = 0.0f;
    }
    // folded weight cast+transpose (with /64 scale compensation)
    if (i < 64 * 128) {                       // Wt2: [f=128][k=64]
        int f = i / 64, k = i % 64;
        Wt2[i] = bf16_rne(W2[k * 128 + f] * 0.015625f);
    } else if (i < 64 * 128 + 128 * 256) {    // Wt3: [f=256][k=128]
        int j = i - 64 * 128;
        int f = j / 128, k = j % 128;
        Wt3[j] = bf16_rne(W3[k * 256 + f] * 0.015625f);
    }
}

// ---- CSR fill: no atomic; slot = base[copy][dst] + rank-within-copy --------
__global__ void k_fill(const int* __restrict__ row, const int* __restrict__ col,
                       const int* __restrict__ base, const int* __restrict__ pos,
                       int* __restrict__ csr_src, int E) {
    int e = blockIdx.x * blockDim.x + threadIdx.x;
    if (e >= E) return;
    int c8 = (e >> 8) & 7;
    csr_src[base[c8 * N_NODES + col[e]] + pos[e]] = row[e];
}

// ---- fused layer 1: p1 = dv*(xs[v]+Σxs[r]); X = enc(64*dv*relu(p1 W1+b1)) --
__global__ void k_layer1(const float* __restrict__ xs, const float* __restrict__ dinv,
                         const int* __restrict__ rowptr, const int* __restrict__ csr_src,
                         const float* __restrict__ W1, const float* __restrict__ b1,
                         unsigned char* __restrict__ out, int N) {
    int v = blockIdx.x * blockDim.x + threadIdx.x;
    if (v >= N) return;
    float a0 = xs[v * 3 + 0];
    float a1 = xs[v * 3 + 1];
    float a2 = xs[v * 3 + 2];
    int j = rowptr[v];
    int j1 = rowptr[v + 1];
    for (; j + 4 <= j1; j += 4) {
        int r0 = csr_src[j + 0], r1 = csr_src[j + 1];
        int r2 = csr_src[j + 2], r3 = csr_src[j + 3];
        float x00 = xs[r0 * 3 + 0], x01 = xs[r0 * 3 + 1], x02 = xs[r0 * 3 + 2];
        float x10 = xs[r1 * 3 + 0], x11 = xs[r1 * 3 + 1], x12 = xs[r1 * 3 + 2];
        float x20 = xs[r2 * 3 + 0], x21 = xs[r2 * 3 + 1], x22 = xs[r2 * 3 + 2];
        float x30 = xs[r3 * 3 + 0], x31 = xs[r3 * 3 + 1], x32 = xs[r3 * 3 + 2];
        a0 += x00; a1 += x01; a2 += x02;
        a0 += x10; a1 += x11; a2 += x12;
        a0 += x20; a1 += x21; a2 += x22;
        a0 += x30; a1 += x31; a2 += x32;
    }
    for (; j < j1; ++j) {  // dead with padded degrees
        int r = csr_src[j];
        a0 += xs[r * 3 + 0];
        a1 += xs[r * 3 + 1];
        a2 += xs[r * 3 + 2];
    }
    float dv = dinv[v];
    float p0 = dv * a0, p1 = dv * a1, p2 = dv * a2;
    float dv64 = dv * 64.0f;  // pre-scale for next prop + x64 codec shift
    unsigned char* ov = out + (long)v * 64;
#pragma unroll
    for (int f = 0; f < 64; f += 4) {
        float s[4];
#pragma unroll
        for (int t = 0; t < 4; ++t) {
            float sv = fmaf(p0, W1[f + t],
                       fmaf(p1, W1[64 + f + t],
                       fmaf(p2, W1[128 + f + t], b1[f + t])));
            s[t] = fmaxf(sv, 0.0f) * dv64;
        }
        *(unsigned*)(ov + f) = enc4(s[0], s[1], s[2], s[3]);
    }
}

// ---- FUSED prop + MFMA GEMM per 16-row m-tile; optional fused mean-pool ----
// Gather = R15 2-row interleaved structure (4 waves, R2/R4 shape). Inputs h
// are 8-bit (x64 scale); decode = 1 HW cvt_pk per 2 features. plds holds bf16
// of 64*p; Wt is pre-divided by 64 so MFMA output is true-scale. Phase 2 =
// verified R9/R11 MFMA layout.
template <int K, int F, bool PRESCALE, bool POOL>
__global__ __launch_bounds__(256) void k_fused(
        const unsigned char* __restrict__ h, const float* __restrict__ dinv,
        const int* __restrict__ rowptr, const int* __restrict__ csr_src,
        const unsigned short* __restrict__ Wt, const float* __restrict__ b,
        unsigned char* __restrict__ out, const int* __restrict__ batch,
        float* __restrict__ psum, int N) {
    constexpr int NF = F / 16;    // f-tiles: 8 (F=128) / 16 (F=256)
    constexpr int FPW = NF / 4;   // f-tiles per wave: 2 / 4
    constexpr int KB = K / 32;    // k-blocks: 2 / 4
    constexpr int KL = K / 64;    // features (bytes) per lane in prop: 1 / 2
    constexpr int PADK = K + 8;
    __shared__ unsigned short plds[16][PADK];
    int wave = threadIdx.x >> 6;
    int lane = threadIdx.x & 63;
    int m0 = blockIdx.x * 16;

    // ---- phase 1: propagation into LDS, rows processed in pairs ----
    for (int pr = 0; pr < 2; ++pr) {
        int va = m0 + wave * 4 + pr * 2;
        int vb = va + 1;
        float acca[KL], accb[KL];
        const unsigned char* hva = h + (long)va * K + lane * KL;
        const unsigned char* hvb = h + (long)vb * K + lane * KL;
        if (KL == 2) {
            unsigned ua = *(const unsigned short*)hva;
            unsigned ub = *(const unsigned short*)hvb;
            dq2(ua, acca[0], acca[1]);
            dq2(ub, accb[0], accb[1]);
        } else {
            acca[0] = dq1(hva[0]);
            accb[0] = dq1(hvb[0]);
        }
        int ja  = __builtin_amdgcn_readfirstlane(rowptr[va]);
        int j1a = __builtin_amdgcn_readfirstlane(rowptr[va + 1]);
        int jb  = j1a;
        int j1b = __builtin_amdgcn_readfirstlane(rowptr[vb + 1]);
        while (ja + 8 <= j1a && jb + 8 <= j1b) {
            int ra[8], rb[8];
#pragma unroll
            for (int u = 0; u < 8; ++u) ra[u] = csr_src[ja + u];
#pragma unroll
            for (int u = 0; u < 8; ++u) rb[u] = csr_src[jb + u];
            if (KL == 2) {
                unsigned ta[8], tb[8];
#pragma unroll
                for (int u = 0; u < 8; ++u)
                    ta[u] = *(const unsigned short*)(h + (long)ra[u] * K + lane * 2);
#pragma unroll
                for (int u = 0; u < 8; ++u)
                    tb[u] = *(const unsigned short*)(h + (long)rb[u] * K + lane * 2);
#pragma unroll
                for (int u = 0; u < 8; ++u) {
                    float lo, hi;
                    dq2(ta[u], lo, hi);
                    acca[0] += lo;
                    acca[1] += hi;
                }
#pragma unroll
                for (int u = 0; u < 8; ++u) {
                    float lo, hi;
                    dq2(tb[u], lo, hi);
                    accb[0] += lo;
                    accb[1] += hi;
                }
            } else {
                unsigned char ta[8], tb[8];
#pragma unroll
                for (int u = 0; u < 8; ++u) ta[u] = h[(long)ra[u] * K + lane];
#pragma unroll
                for (int u = 0; u < 8; ++u) tb[u] = h[(long)rb[u] * K + lane];
#pragma unroll
                for (int u = 0; u < 8; ++u) acca[0] += dq1(ta[u]);
#pragma unroll
                for (int u = 0; u < 8; ++u) accb[0] += dq1(tb[u]);
            }
            ja += 8;
            jb += 8;
        }
        for (; ja + 8 <= j1a; ja += 8) {
            int r[8];
#pragma unroll
            for (int u = 0; u < 8; ++u) r[u] = csr_src[ja + u];
            if (KL == 2) {
                unsigned tv[8];
#pragma unroll
                for (int u = 0; u < 8; ++u)
                    tv[u] = *(const unsigned short*)(h + (long)r[u] * K + lane * 2);
#pragma unroll
                for (int u = 0; u < 8; ++u) {
                    float lo, hi;
                    dq2(tv[u], lo, hi);
                    acca[0] += lo;
                    acca[1] += hi;
                }
            } else {
                unsigned char tv[8];
#pragma unroll
                for (int u = 0; u < 8; ++u) tv[u] = h[(long)r[u] * K + lane];
#pragma unroll
                for (int u = 0; u < 8; ++u) acca[0] += dq1(tv[u]);
            }
        }
        for (; ja < j1a; ++ja) {  // dead with padded degrees
            int r = csr_src[ja];
            if (KL == 2) {
                unsigned u = *(const unsigned short*)(h + (long)r * K + lane * 2);
                float lo, hi;
                dq2(u, lo, hi);
                acca[0] += lo;
                acca[1] += hi;
            } else {
                acca[0] += dq1(h[(long)r * K + lane]);
            }
        }
        for (; jb + 8 <= j1b; jb += 8) {
            int r[8];
#pragma unroll
            for (int u = 0; u < 8; ++u) r[u] = csr_src[jb + u];
            if (KL == 2) {
                unsigned tv[8];
#pragma unroll
                for (int u = 0; u < 8; ++u)
                    tv[u] = *(const unsigned short*)(h + (long)r[u] * K + lane * 2);
#pragma unroll
                for (int u = 0; u < 8; ++u) {
                    float lo, hi;
                    dq2(tv[u], lo, hi);
                    accb[0] += lo;
                    accb[1] += hi;
                }
            } else {
                unsigned char tv[8];
#pragma unroll
                for (int u = 0; u < 8; ++u) tv[u] = h[(long)r[u] * K + lane];
#pragma unroll
                for (int u = 0; u < 8; ++u) accb[0] += dq1(tv[u]);
            }
        }
        for (; jb < j1b; ++jb) {  // dead with padded degrees
            int r = csr_src[jb];
            if (KL == 2) {
                unsigned u = *(const unsigned short*)(h + (long)r * K + lane * 2);
                float lo, hi;
                dq2(u, lo, hi);
                accb[0] += lo;
                accb[1] += hi;
            } else {
                accb[0] += dq1(h[(long)r * K + lane]);
            }
        }
        float da = dinv[va];
        float db = dinv[vb];
        int rla = wave * 4 + pr * 2;
        if (KL == 2) {
            unsigned pa = (unsigned)bf16_rne(da * acca[0]) | ((unsigned)bf16_rne(da * acca[1]) << 16);
            unsigned pb = (unsigned)bf16_rne(db * accb[0]) | ((unsigned)bf16_rne(db * accb[1]) << 16);
            *(unsigned*)&plds[rla][lane * 2] = pa;
            *(unsigned*)&plds[rla + 1][lane * 2] = pb;
        } else {
            plds[rla][lane] = bf16_rne(da * acca[0]);
            plds[rla + 1][lane] = bf16_rne(db * accb[0]);
        }
    }
    __syncthreads();

    // ---- phase 2: MFMA (layout verified R9/R11) ----
    int quad = lane >> 4;
    int l16 = lane & 15;
    bf16x8 afr[KB];
#pragma unroll
    for (int kb = 0; kb < KB; ++kb)
        afr[kb] = *(const bf16x8*)(const void*)&plds[l16][kb * 32 + quad * 8];
#pragma unroll
    for (int fi = 0; fi < FPW; ++fi) {
        int f0 = (wave * FPW + fi) * 16;
        const unsigned short* wrow = Wt + (long)(f0 + l16) * K + quad * 8;
        f32x4 acc4 = {0.f, 0.f, 0.f, 0.f};
#pragma unroll
        for (int kb = 0; kb < KB; ++kb) {
            bf16x8 bb = *(const bf16x8*)(const void*)(wrow + kb * 32);
            acc4 = __builtin_amdgcn_mfma_f32_16x16x32_bf16(afr[kb], bb, acc4, 0, 0, 0);
        }
        float bias = b[f0 + l16];
        if (POOL) {
            int g0 = batch[m0];
            int g15 = batch[m0 + 15];
            if (g0 == g15) {  // uniform block (all but ~15 of 3125)
                float s = fmaxf(acc4[0] + bias, 0.0f);
                s += fmaxf(acc4[1] + bias, 0.0f);
                s += fmaxf(acc4[2] + bias, 0.0f);
                s += fmaxf(acc4[3] + bias, 0.0f);
                s += __shfl_xor(s, 16);
                s += __shfl_xor(s, 32);
                if (quad == 0) atomicAdd(&psum[g0 * 256 + f0 + l16], s);
            } else {  // graph boundary inside block: per-element atomics
#pragma unroll
                for (int r = 0; r < 4; ++r) {
                    int m = m0 + quad * 4 + r;
                    float val = fmaxf(acc4[r] + bias, 0.0f);
                    atomicAdd(&psum[batch[m] * 256 + f0 + l16], val);
                }
            }
        } else {
#pragma unroll
            for (int r = 0; r < 4; ++r) {
                int m = m0 + quad * 4 + r;
                float val = fmaxf(acc4[r] + bias, 0.0f);
                if (PRESCALE) val *= dinv[m] * 64.0f;  // prop pre-scale + codec shift
                out[(long)m * F + f0 + l16] = (unsigned char)enc1(val);
            }
        }
    }
}

// ---- final FC --------------------------------------------------------------
__global__ void k_fc(const float* __restrict__ psum, const float* __restrict__ pcnt,
                     const float* __restrict__ Wfc, const float* __restrict__ bfc,
                     float* __restrict__ out) {
    int tid = blockIdx.x * blockDim.x + threadIdx.x;
    if (tid >= NUM_GRAPHS * NUM_CLASSES) return;
    int g = tid / NUM_CLASSES;
    int c = tid % NUM_CLASSES;
    float s = 0.0f;
#pragma unroll 8
    for (int k = 0; k < 256; ++k) s = fmaf(psum[g * 256 + k], Wfc[k * NUM_CLASSES + c], s);
    float cnt = pcnt[g];
    cnt = cnt > 1.0f ? cnt : 1.0f;
    out[tid] = s / cnt + bfc[c];
}

extern "C" void kernel_launch(void* const* d_in, const int* in_sizes, int n_in,
                              void* d_out, int out_size, void* d_ws, size_t ws_size,
                              hipStream_t stream) {
    const float* x     = (const float*)d_in[0];
    const int*   ei    = (const int*)d_in[1];
    const int*   batch = (const int*)d_in[2];
    const float* W1    = (const float*)d_in[3];
    const float* b1    = (const float*)d_in[4];
    const float* W2    = (const float*)d_in[5];
    const float* b2    = (const float*)d_in[6];
    const float* W3    = (const float*)d_in[7];
    const float* b3    = (const float*)d_in[8];
    const float* Wfc   = (const float*)d_in[9];
    const float* bfc   = (const float*)d_in[10];
    float* out = (float*)d_out;

    const int* row = ei;            // src
    const int* col = ei + N_EDGES;  // dst

    // workspace layout, 16B-aligned; sentinel row at index N_NODES.
    float*  xs   = (float*)d_ws;                         // (N+1)*3 f32 (padded to 150004)
    float*  dinv = xs + 150004;                          // N
    float*  psum = dinv + N_NODES;                       // 16*256
    float*  pcnt = psum + NUM_GRAPHS * 256;              // 16
    unsigned char* X = (unsigned char*)(pcnt + NUM_GRAPHS);      // (N+1)*64 B
    unsigned char* Y = X + (size_t)(N_NODES + 1) * 64;           // (N+1)*128 B
    unsigned short* Wt2 = (unsigned short*)(Y + (size_t)(N_NODES + 1) * 128);  // 128*64
    unsigned short* Wt3 = Wt2 + 128 * 64;                        // 256*128
    int* degc   = (int*)(Wt3 + 256 * 128);               // 8*N (XCD-local copies)
    int* base   = degc + 8 * N_NODES;                    // 8*N (per-copy slot bases)
    int* rowptr = base + 8 * N_NODES;                    // N+1
    int* csrsrc = rowptr + N_NODES + 1;                  // CSR_CAP (padded)
    int* pos    = csrsrc + CSR_CAP;                      // E
    int* bsum   = pos + N_EDGES;                         // SCAN_BLOCKS

    // single memset: degc must be zero before k_deg's atomics
    hipMemsetAsync(degc, 0, 8 * N_NODES * sizeof(int), stream);

    // ---- CSR build + norms + pre-scaled x + weight casts ----
    // (k_deg block 0 also zeroes psum/pcnt and the X/Y sentinel rows)
    k_deg<<<nblk(N_EDGES), 256, 0, stream>>>(col, degc, pos, psum, X, Y, N_EDGES);
    k_scan1<<<SCAN_BLOCKS, 256, 0, stream>>>(degc, rowptr, bsum, batch, pcnt, N_NODES);
    k_scan3<<<SCAN_BLOCKS, 256, 0, stream>>>(rowptr, bsum, degc, base, dinv, x, xs,
                                             csrsrc, W2, W3, Wt2, Wt3, N_NODES);
    k_fill<<<nblk(N_EDGES), 256, 0, stream>>>(row, col, base, pos, csrsrc, N_EDGES);

    // ---- layer 1 (fused prop+linear): X = enc(64*d*relu((A~x)W1+b1)) -------
    k_layer1<<<nblk(N_NODES), 256, 0, stream>>>(xs, dinv, rowptr, csrsrc, W1, b1, X, N_NODES);

    int mtiles = N_NODES / 16;  // 3125, exact

    // ---- layer 2 fused: Y = enc(64*d*relu((A~-apply X) W2 + b2)) -----------
    k_fused<64, 128, true, false><<<mtiles, 256, 0, stream>>>(
        X, dinv, rowptr, csrsrc, Wt2, b2, Y, batch, psum, N_NODES);

    // ---- layer 3 fused + POOL: psum += relu((A~-apply Y) W3 + b3) ----------
    k_fused<128, 256, false, true><<<mtiles, 256, 0, stream>>>(
        Y, dinv, rowptr, csrsrc, Wt3, b3, (unsigned char*)nullptr, batch, psum, N_NODES);

    // ---- FC ----
    k_fc<<<nblk(NUM_GRAPHS * NUM_CLASSES), 256, 0, stream>>>(psum, pcnt, Wfc, bfc, out);
}